// Round 1
// baseline (513.895 us; speedup 1.0000x reference)
//
#include <hip/hip_runtime.h>

typedef __bf16 bf16_t;
typedef __bf16 bf16x4 __attribute__((ext_vector_type(4)));
typedef __bf16 bf16x8 __attribute__((ext_vector_type(8)));
typedef float floatx4 __attribute__((ext_vector_type(4)));

#define G_GRAPHS 64
#define N_NODES 2000
#define N_EDGES 64000
#define BATCH 10000
#define TED_ 512
#define NOISE_ 128
#define PACDIM_ 6400
#define D0_ 1024
#define D1_ 512
#define MROWS 1000   // BATCH / PAC

// ---------------- async global->LDS helper (16B per lane) ----------------
__device__ __forceinline__ void glds16(const void* g, void* l) {
    __builtin_amdgcn_global_load_lds(
        (__attribute__((address_space(1))) void*)(g),
        (__attribute__((address_space(3))) void*)(l), 16, 0, 0);
}

// ---------------- kernel 1: per-graph GCN + gnoise[G,128] ----------------
__global__ __launch_bounds__(512) void gcn_kernel(
    const float* __restrict__ graphs_x,   // [G,N]
    const int*   __restrict__ edge_index, // [G,2,E]
    const float* __restrict__ gcn_w, const float* __restrict__ gcn_b,
    const float* __restrict__ gme_w,      // [2032,128]
    float* __restrict__ gnoise)           // [G,128]
{
    __shared__ float xs[N_NODES];
    __shared__ float degs[N_NODES];
    __shared__ float outs[N_NODES];
    __shared__ float part[4][128];
    const int g = blockIdx.x;
    const int tid = threadIdx.x;
    const int* src = edge_index + (size_t)g * 2 * N_EDGES;
    const int* dst = src + N_EDGES;

    for (int n = tid; n < N_NODES; n += 512) {
        xs[n] = graphs_x[(size_t)g * N_NODES + n];
        degs[n] = 1.0f;   // self-loop
        outs[n] = 0.0f;
    }
    __syncthreads();
    for (int e = tid; e < N_EDGES; e += 512)
        atomicAdd(&degs[dst[e]], 1.0f);
    __syncthreads();
    for (int n = tid; n < N_NODES; n += 512)
        degs[n] = rsqrtf(degs[n]);        // degs now holds dinv
    __syncthreads();
    for (int e = tid; e < N_EDGES; e += 512) {
        int s = src[e], d = dst[e];
        atomicAdd(&outs[d], xs[s] * degs[s] * degs[d]);
    }
    __syncthreads();
    const float w = gcn_w[0], b = gcn_b[0];
    for (int n = tid; n < N_NODES; n += 512) {
        float di = degs[n];
        outs[n] = w * (outs[n] + xs[n] * di * di) + b;  // gcn_out[g][n]
    }
    __syncthreads();
    // gnoise[g][j] = sum_n outs[n] * gme_w[n*128+j]
    const int j = tid & 127, ch = tid >> 7;
    float acc = 0.f;
    const int n0 = ch * 500;
    for (int n = n0; n < n0 + 500; n++)
        acc += outs[n] * gme_w[(size_t)n * 128 + j];
    part[ch][j] = acc;
    __syncthreads();
    if (tid < 128)
        gnoise[(size_t)g * 128 + tid] =
            part[0][tid] + part[1][tid] + part[2][tid] + part[3][tid];
}

// ---------------- kernel 2: pack input_ (fp32) -> A (bf16) ----------------
__global__ __launch_bounds__(256) void pack_input_kernel(
    const float* __restrict__ in, bf16_t* __restrict__ A)
{
    int idx = blockIdx.x * 256 + threadIdx.x;       // over BATCH*512/4
    if (idx >= BATCH * TED_ / 4) return;
    float4 v = ((const float4*)in)[idx];
    int b = idx >> 7;                 // row of input_ (512/4 = 128 vec4 per row)
    int c = (idx & 127) << 2;
    int r = b / 10, slot = b - r * 10;
    bf16x4 o = { (bf16_t)v.x, (bf16_t)v.y, (bf16_t)v.z, (bf16_t)v.w };
    *(bf16x4*)(A + (size_t)r * PACDIM_ + slot * 640 + c) = o;
}

// ------- kernel 3: meta_emb + noise -> A noise columns (one wave per row) -------
__global__ __launch_bounds__(256) void meta_noise_kernel(
    const float* __restrict__ chain, const float* __restrict__ metadata,
    const int* __restrict__ graph_ids,
    const float* __restrict__ meta_w, const float* __restrict__ meta_b,
    const float* __restrict__ gme_w, const float* __restrict__ gme_b,
    const float* __restrict__ gnoise, bf16_t* __restrict__ A)
{
    int wid = (blockIdx.x * 256 + threadIdx.x) >> 6;
    int lane = threadIdx.x & 63;
    if (wid >= BATCH) return;
    const int b = wid;
    // meta_emb[k] on lanes k<32
    float me = 0.f;
    if (lane < 32) {
        me = meta_b[lane] + chain[b] * meta_w[lane];
        for (int i = 1; i < 16; i++)
            me += metadata[(size_t)b * 15 + (i - 1)] * meta_w[(size_t)i * 32 + lane];
        me = me > 0.f ? me : 0.f;
    }
    const int gid = graph_ids[b];
    const int j1 = lane, j2 = lane + 64;
    float n1 = gnoise[(size_t)gid * 128 + j1] + gme_b[j1];
    float n2 = gnoise[(size_t)gid * 128 + j2] + gme_b[j2];
    for (int k = 0; k < 32; k++) {
        float mk = __shfl(me, k, 64);
        const float* wrow = gme_w + (size_t)(N_NODES + k) * 128;
        n1 += mk * wrow[j1];
        n2 += mk * wrow[j2];
    }
    int r = b / 10, slot = b - r * 10;
    bf16_t* dp = A + (size_t)r * PACDIM_ + slot * 640 + TED_;
    dp[j1] = (bf16_t)n1;
    dp[j2] = (bf16_t)n2;
}

// -------- kernel 4: transpose-convert W [R,C] fp32 -> Wt [C,R] bf16 --------
__global__ __launch_bounds__(256) void transpose_bf16_kernel(
    const float* __restrict__ W, bf16_t* __restrict__ Wt, int R, int C)
{
    __shared__ float t[32][33];
    int c0 = blockIdx.x * 32, r0 = blockIdx.y * 32;
    int tx = threadIdx.x & 31, ty = threadIdx.x >> 5;  // 8 y-rows per pass
    for (int yy = ty; yy < 32; yy += 8)
        t[yy][tx] = W[(size_t)(r0 + yy) * C + c0 + tx];
    __syncthreads();
    for (int yy = ty; yy < 32; yy += 8)
        Wt[(size_t)(c0 + yy) * R + r0 + tx] = (bf16_t)t[tx][yy];
}

// -------- kernel 5: C = leaky(A[M,K] @ Bt[N,K]^T + bias, 0.2) -> bf16 --------
// m97 structure: BM=BN=128, BK=32, 256 thr = 4 waves, each wave 64x64 (4x4 frags)
__global__ __launch_bounds__(256) void gemm_bt_kernel(
    const bf16_t* __restrict__ A,   // [M,K] row-major
    const bf16_t* __restrict__ Bt,  // [N,K] row-major (i.e. B transposed)
    const float* __restrict__ bias, // [N]
    bf16_t* __restrict__ C,         // [M,N]
    int M, int N, int K)
{
    __shared__ __align__(16) bf16_t As[128 * 32];
    __shared__ __align__(16) bf16_t Bs[128 * 32];
    const int tid = threadIdx.x;
    const int wave = tid >> 6;
    const int lane = tid & 63;
    const int mBase = blockIdx.y * 128;
    const int nBase = blockIdx.x * 128;
    const int wm = (wave & 1) * 64;
    const int wn = (wave >> 1) * 64;

    floatx4 acc[4][4] = {};

    // staging addresses: chunk c in [0,512): row = c>>2, k-offset = (c&3)*8
    const int c0 = tid, c1 = tid + 256;
    const int rA0 = c0 >> 2, k80 = (c0 & 3) * 8;
    const int rA1 = c1 >> 2, k81 = (c1 & 3) * 8;
    int gm0 = mBase + rA0; if (gm0 > M - 1) gm0 = M - 1;
    int gm1 = mBase + rA1; if (gm1 > M - 1) gm1 = M - 1;
    const bf16_t* aP0 = A + (size_t)gm0 * K + k80;
    const bf16_t* aP1 = A + (size_t)gm1 * K + k81;
    const bf16_t* bP0 = Bt + (size_t)(nBase + rA0) * K + k80;
    const bf16_t* bP1 = Bt + (size_t)(nBase + rA1) * K + k81;
    char* lA0 = (char*)As + wave * 1024;
    char* lA1 = (char*)As + 4096 + wave * 1024;
    char* lB0 = (char*)Bs + wave * 1024;
    char* lB1 = (char*)Bs + 4096 + wave * 1024;

    // LDS fragment read pointers (constant over K loop)
    const int kq = (lane >> 4) * 8;    // k-chunk within BK=32
    const int mr = lane & 15;
    const bf16x8* ra[4]; const bf16x8* rb[4];
    for (int i = 0; i < 4; i++)
        ra[i] = (const bf16x8*)&As[(wm + i * 16 + mr) * 32 + kq];
    for (int j = 0; j < 4; j++)
        rb[j] = (const bf16x8*)&Bs[(wn + j * 16 + mr) * 32 + kq];

    for (int k0 = 0; k0 < K; k0 += 32) {
        __syncthreads();
        glds16(aP0 + k0, lA0);
        glds16(aP1 + k0, lA1);
        glds16(bP0 + k0, lB0);
        glds16(bP1 + k0, lB1);
        __syncthreads();
        bf16x8 af[4], bfr[4];
        for (int i = 0; i < 4; i++) af[i] = *ra[i];
        for (int j = 0; j < 4; j++) bfr[j] = *rb[j];
        for (int i = 0; i < 4; i++)
            for (int j = 0; j < 4; j++)
                acc[i][j] = __builtin_amdgcn_mfma_f32_16x16x32_bf16(
                    af[i], bfr[j], acc[i][j], 0, 0, 0);
    }

    // epilogue: C/D layout col=lane&15, row=(lane>>4)*4+reg  [m89-verified]
    const int rq = (lane >> 4) * 4;
    const int cn = lane & 15;
    for (int j = 0; j < 4; j++) {
        int col = nBase + wn + j * 16 + cn;
        float bv = bias[col];
        for (int i = 0; i < 4; i++) {
            for (int r = 0; r < 4; r++) {
                int rowm = mBase + wm + i * 16 + rq + r;
                if (rowm < M) {
                    float v = acc[i][j][r] + bv;
                    v = v > 0.f ? v : 0.2f * v;
                    C[(size_t)rowm * N + col] = (bf16_t)v;
                }
            }
        }
    }
}

// -------- kernel 6: out[r] = H2[r,:512] . w2 + b2  (one wave per row) --------
__global__ __launch_bounds__(256) void final_kernel(
    const bf16_t* __restrict__ H2, const float* __restrict__ w2,
    const float* __restrict__ b2, float* __restrict__ out)
{
    int wid = (blockIdx.x * 256 + threadIdx.x) >> 6;
    int lane = threadIdx.x & 63;
    if (wid >= MROWS) return;
    const bf16_t* row = H2 + (size_t)wid * D1_;
    float s = 0.f;
    for (int i = 0; i < 8; i++) {
        int c = i * 64 + lane;
        s += (float)row[c] * w2[c];
    }
    for (int off = 32; off; off >>= 1) s += __shfl_down(s, off, 64);
    if (lane == 0) out[wid] = s + b2[0];
}

// ---------------------------- launcher ----------------------------
extern "C" void kernel_launch(void* const* d_in, const int* in_sizes, int n_in,
                              void* d_out, int out_size, void* d_ws, size_t ws_size,
                              hipStream_t stream)
{
    const float* input_    = (const float*)d_in[0];
    const float* graphs_x  = (const float*)d_in[1];
    const int*   edge_idx  = (const int*)  d_in[2];
    const int*   graph_ids = (const int*)  d_in[3];
    const float* chain     = (const float*)d_in[4];
    const float* metadata  = (const float*)d_in[5];
    const float* gcn_w     = (const float*)d_in[6];
    const float* gcn_b     = (const float*)d_in[7];
    const float* meta_w    = (const float*)d_in[8];
    const float* meta_b    = (const float*)d_in[9];
    const float* gme_w     = (const float*)d_in[10];
    const float* gme_b     = (const float*)d_in[11];
    const float* seq_w0    = (const float*)d_in[12];
    const float* seq_b0    = (const float*)d_in[13];
    const float* seq_w1    = (const float*)d_in[14];
    const float* seq_b1    = (const float*)d_in[15];
    const float* seq_w2    = (const float*)d_in[16];
    const float* seq_b2    = (const float*)d_in[17];
    float* out = (float*)d_out;

    char* ws = (char*)d_ws;
    // workspace layout (all 256B-aligned)
    float*  gnoise = (float*)(ws + 0);                        //  64*128*4   = 32768
    bf16_t* Abuf   = (bf16_t*)(ws + 32768);                   // 1000*6400*2 = 12800000
    bf16_t* W0t    = (bf16_t*)(ws + 12832768);                // 1024*6400*2 = 13107200
    bf16_t* W1t    = (bf16_t*)(ws + 25939968);                //  512*1024*2 = 1048576
    bf16_t* H1     = (bf16_t*)(ws + 26988544);                // 1000*1024*2 = 2048000
    bf16_t* H2     = (bf16_t*)(ws + 29036544);                // 1000*512*2  = 1024000
    // total ~30.1 MB

    gcn_kernel<<<G_GRAPHS, 512, 0, stream>>>(graphs_x, edge_idx, gcn_w, gcn_b,
                                             gme_w, gnoise);
    pack_input_kernel<<<(BATCH * TED_ / 4 + 255) / 256, 256, 0, stream>>>(input_, Abuf);
    meta_noise_kernel<<<(BATCH * 64 + 255) / 256, 256, 0, stream>>>(
        chain, metadata, graph_ids, meta_w, meta_b, gme_w, gme_b, gnoise, Abuf);
    transpose_bf16_kernel<<<dim3(D0_ / 32, PACDIM_ / 32), 256, 0, stream>>>(
        seq_w0, W0t, PACDIM_, D0_);
    transpose_bf16_kernel<<<dim3(D1_ / 32, D0_ / 32), 256, 0, stream>>>(
        seq_w1, W1t, D0_, D1_);
    gemm_bt_kernel<<<dim3(D0_ / 128, (MROWS + 127) / 128), 256, 0, stream>>>(
        Abuf, W0t, seq_b0, H1, MROWS, D0_, PACDIM_);
    gemm_bt_kernel<<<dim3(D1_ / 128, (MROWS + 127) / 128), 256, 0, stream>>>(
        H1, W1t, seq_b1, H2, MROWS, D1_, D0_);
    final_kernel<<<(MROWS * 64 + 255) / 256, 256, 0, stream>>>(H2, seq_w2, seq_b2, out);
}

// Round 2
// 302.193 us; speedup vs baseline: 1.7006x; 1.7006x over previous
//
#include <hip/hip_runtime.h>

typedef __bf16 bf16_t;
typedef __bf16 bf16x4 __attribute__((ext_vector_type(4)));
typedef __bf16 bf16x8 __attribute__((ext_vector_type(8)));
typedef float floatx4 __attribute__((ext_vector_type(4)));

#define G_GRAPHS 64
#define N_NODES 2000
#define N_EDGES 64000
#define BATCH 10000
#define TED_ 512
#define NOISE_ 128
#define PACDIM_ 6400
#define D0_ 1024
#define D1_ 512
#define MROWS 1000   // BATCH / PAC
#define ESPLIT 8
#define EPB (N_EDGES / ESPLIT)   // 8000 edges per block

// ---------------- async global->LDS helper (16B per lane) ----------------
__device__ __forceinline__ void glds16(const void* g, void* l) {
    __builtin_amdgcn_global_load_lds(
        (__attribute__((address_space(1))) void*)(g),
        (__attribute__((address_space(3))) void*)(l), 16, 0, 0);
}

// ---------------- kernel 0: zero degs+outs (contiguous region) ----------------
__global__ __launch_bounds__(256) void zero_kernel(float4* __restrict__ p, int n4) {
    int i = blockIdx.x * 256 + threadIdx.x;
    if (i < n4) p[i] = make_float4(0.f, 0.f, 0.f, 0.f);
}

// ---------- kernel 1a: degree histogram, split over edges ----------
__global__ __launch_bounds__(512) void deg_kernel(
    const int* __restrict__ edge_index, float* __restrict__ degs)
{
    __shared__ float h[N_NODES];
    const int g = blockIdx.y, s = blockIdx.x, tid = threadIdx.x;
    for (int n = tid; n < N_NODES; n += 512) h[n] = 0.f;
    __syncthreads();
    const int* dst = edge_index + (size_t)g * 2 * N_EDGES + N_EDGES + s * EPB;
    for (int e = tid; e < EPB; e += 512) atomicAdd(&h[dst[e]], 1.0f);
    __syncthreads();
    float* dg = degs + (size_t)g * N_NODES;
    for (int n = tid; n < N_NODES; n += 512) {
        float v = h[n];
        if (v != 0.f) atomicAdd(&dg[n], v);
    }
}

// ---------- kernel 1b: message pass, split over edges ----------
__global__ __launch_bounds__(512) void msg_kernel(
    const float* __restrict__ graphs_x, const int* __restrict__ edge_index,
    const float* __restrict__ degs, float* __restrict__ outs)
{
    __shared__ float xsl[N_NODES];
    __shared__ float dvl[N_NODES];
    __shared__ float oh[N_NODES];
    const int g = blockIdx.y, s = blockIdx.x, tid = threadIdx.x;
    const float* xg = graphs_x + (size_t)g * N_NODES;
    const float* dgg = degs + (size_t)g * N_NODES;
    for (int n = tid; n < N_NODES; n += 512) {
        xsl[n] = xg[n];
        dvl[n] = rsqrtf(dgg[n] + 1.0f);   // +1 self-loop
        oh[n] = 0.f;
    }
    __syncthreads();
    const int* src = edge_index + (size_t)g * 2 * N_EDGES + s * EPB;
    const int* dst = src + N_EDGES;
    for (int e = tid; e < EPB; e += 512) {
        int ss = src[e], dd = dst[e];
        atomicAdd(&oh[dd], xsl[ss] * dvl[ss] * dvl[dd]);
    }
    __syncthreads();
    float* og = outs + (size_t)g * N_NODES;
    for (int n = tid; n < N_NODES; n += 512) {
        float v = oh[n];
        if (v != 0.f) atomicAdd(&og[n], v);
    }
}

// ---------- kernel 1c: finish gcn + gnoise[G,128] GEMV ----------
__global__ __launch_bounds__(512) void gnoise_kernel(
    const float* __restrict__ graphs_x, const float* __restrict__ degs,
    const float* __restrict__ outs,
    const float* __restrict__ gcn_w, const float* __restrict__ gcn_b,
    const float* __restrict__ gme_w, float* __restrict__ gnoise)
{
    __shared__ float of[N_NODES];
    __shared__ float part[4][128];
    const int g = blockIdx.x, tid = threadIdx.x;
    const float w = gcn_w[0], b = gcn_b[0];
    for (int n = tid; n < N_NODES; n += 512) {
        float di2 = 1.0f / (degs[(size_t)g * N_NODES + n] + 1.0f);
        of[n] = w * (outs[(size_t)g * N_NODES + n]
                     + graphs_x[(size_t)g * N_NODES + n] * di2) + b;
    }
    __syncthreads();
    const int j = tid & 127, ch = tid >> 7;
    float acc = 0.f;
    const int n0 = ch * 500;
    for (int n = n0; n < n0 + 500; n++)
        acc += of[n] * gme_w[(size_t)n * 128 + j];
    part[ch][j] = acc;
    __syncthreads();
    if (tid < 128)
        gnoise[(size_t)g * 128 + tid] =
            part[0][tid] + part[1][tid] + part[2][tid] + part[3][tid];
}

// ---------------- kernel 2: pack input_ (fp32) -> A (bf16) ----------------
__global__ __launch_bounds__(256) void pack_input_kernel(
    const float* __restrict__ in, bf16_t* __restrict__ A)
{
    int idx = blockIdx.x * 256 + threadIdx.x;       // over BATCH*512/4
    if (idx >= BATCH * TED_ / 4) return;
    float4 v = ((const float4*)in)[idx];
    int b = idx >> 7;
    int c = (idx & 127) << 2;
    int r = b / 10, slot = b - r * 10;
    bf16x4 o = { (bf16_t)v.x, (bf16_t)v.y, (bf16_t)v.z, (bf16_t)v.w };
    *(bf16x4*)(A + (size_t)r * PACDIM_ + slot * 640 + c) = o;
}

// ------- kernel 3: meta_emb + noise -> A noise columns (one wave per row) -------
__global__ __launch_bounds__(256) void meta_noise_kernel(
    const float* __restrict__ chain, const float* __restrict__ metadata,
    const int* __restrict__ graph_ids,
    const float* __restrict__ meta_w, const float* __restrict__ meta_b,
    const float* __restrict__ gme_w, const float* __restrict__ gme_b,
    const float* __restrict__ gnoise, bf16_t* __restrict__ A)
{
    int wid = (blockIdx.x * 256 + threadIdx.x) >> 6;
    int lane = threadIdx.x & 63;
    if (wid >= BATCH) return;
    const int b = wid;
    float me = 0.f;
    if (lane < 32) {
        me = meta_b[lane] + chain[b] * meta_w[lane];
        for (int i = 1; i < 16; i++)
            me += metadata[(size_t)b * 15 + (i - 1)] * meta_w[(size_t)i * 32 + lane];
        me = me > 0.f ? me : 0.f;
    }
    const int gid = graph_ids[b];
    const int j1 = lane, j2 = lane + 64;
    float n1 = gnoise[(size_t)gid * 128 + j1] + gme_b[j1];
    float n2 = gnoise[(size_t)gid * 128 + j2] + gme_b[j2];
    for (int k = 0; k < 32; k++) {
        float mk = __shfl(me, k, 64);
        const float* wrow = gme_w + (size_t)(N_NODES + k) * 128;
        n1 += mk * wrow[j1];
        n2 += mk * wrow[j2];
    }
    int r = b / 10, slot = b - r * 10;
    bf16_t* dp = A + (size_t)r * PACDIM_ + slot * 640 + TED_;
    dp[j1] = (bf16_t)n1;
    dp[j2] = (bf16_t)n2;
}

// -------- kernel 4: transpose-convert W [R,C] fp32 -> Wt [C,R] bf16 --------
__global__ __launch_bounds__(256) void transpose_bf16_kernel(
    const float* __restrict__ W, bf16_t* __restrict__ Wt, int R, int C)
{
    __shared__ float t[32][33];
    int c0 = blockIdx.x * 32, r0 = blockIdx.y * 32;
    int tx = threadIdx.x & 31, ty = threadIdx.x >> 5;
    for (int yy = ty; yy < 32; yy += 8)
        t[yy][tx] = W[(size_t)(r0 + yy) * C + c0 + tx];
    __syncthreads();
    for (int yy = ty; yy < 32; yy += 8)
        Wt[(size_t)(c0 + yy) * R + r0 + tx] = (bf16_t)t[tx][yy];
}

// -------- kernel 5: split-K GEMM partial: P[z] += A[M,Kslice] @ Bt^T --------
// BM=BN=128, BK=32, 256 thr = 4 waves; blockIdx.z = K-split index
__global__ __launch_bounds__(256) void gemm_bt_splitk_kernel(
    const bf16_t* __restrict__ A,   // [M,K] row-major
    const bf16_t* __restrict__ Bt,  // [N,K] row-major
    float* __restrict__ P,          // [S, Mp, N] fp32 partials
    int M, int N, int K, int KS)    // KS = K slice per split
{
    __shared__ __align__(16) bf16_t As[128 * 32];
    __shared__ __align__(16) bf16_t Bs[128 * 32];
    const int tid = threadIdx.x;
    const int wave = tid >> 6;
    const int lane = tid & 63;
    const int mBase = blockIdx.y * 128;
    const int nBase = blockIdx.x * 128;
    const int z = blockIdx.z;
    const int Mp = gridDim.y * 128;
    const int wm = (wave & 1) * 64;
    const int wn = (wave >> 1) * 64;

    floatx4 acc[4][4] = {};

    const int c0 = tid, c1 = tid + 256;
    const int rA0 = c0 >> 2, k80 = (c0 & 3) * 8;
    const int rA1 = c1 >> 2, k81 = (c1 & 3) * 8;
    int gm0 = mBase + rA0; if (gm0 > M - 1) gm0 = M - 1;
    int gm1 = mBase + rA1; if (gm1 > M - 1) gm1 = M - 1;
    const bf16_t* aP0 = A + (size_t)gm0 * K + k80;
    const bf16_t* aP1 = A + (size_t)gm1 * K + k81;
    const bf16_t* bP0 = Bt + (size_t)(nBase + rA0) * K + k80;
    const bf16_t* bP1 = Bt + (size_t)(nBase + rA1) * K + k81;
    char* lA0 = (char*)As + wave * 1024;
    char* lA1 = (char*)As + 4096 + wave * 1024;
    char* lB0 = (char*)Bs + wave * 1024;
    char* lB1 = (char*)Bs + 4096 + wave * 1024;

    const int kq = (lane >> 4) * 8;
    const int mr = lane & 15;
    const bf16x8* ra[4]; const bf16x8* rb[4];
    for (int i = 0; i < 4; i++)
        ra[i] = (const bf16x8*)&As[(wm + i * 16 + mr) * 32 + kq];
    for (int j = 0; j < 4; j++)
        rb[j] = (const bf16x8*)&Bs[(wn + j * 16 + mr) * 32 + kq];

    const int kEnd = z * KS + KS;
    for (int k0 = z * KS; k0 < kEnd; k0 += 32) {
        __syncthreads();
        glds16(aP0 + k0, lA0);
        glds16(aP1 + k0, lA1);
        glds16(bP0 + k0, lB0);
        glds16(bP1 + k0, lB1);
        __syncthreads();
        bf16x8 af[4], bfr[4];
        for (int i = 0; i < 4; i++) af[i] = *ra[i];
        for (int j = 0; j < 4; j++) bfr[j] = *rb[j];
        for (int i = 0; i < 4; i++)
            for (int j = 0; j < 4; j++)
                acc[i][j] = __builtin_amdgcn_mfma_f32_16x16x32_bf16(
                    af[i], bfr[j], acc[i][j], 0, 0, 0);
    }

    // partial store: fp32, no bias/activation; padded rows harmless
    float* Pz = P + (size_t)z * Mp * N;
    const int rq = (lane >> 4) * 4;
    const int cn = lane & 15;
    for (int j = 0; j < 4; j++) {
        int col = nBase + wn + j * 16 + cn;
        for (int i = 0; i < 4; i++)
            for (int r = 0; r < 4; r++) {
                int rowm = mBase + wm + i * 16 + rq + r;
                Pz[(size_t)rowm * N + col] = acc[i][j][r];
            }
    }
}

// -------- kernel 5b: reduce split-K partials + bias + leaky -> bf16 --------
__global__ __launch_bounds__(256) void reduce_bias_leaky_kernel(
    const float* __restrict__ P, const float* __restrict__ bias,
    bf16_t* __restrict__ C, int M, int N, int Mp, int S)
{
    int idx = blockIdx.x * 256 + threadIdx.x;
    int total = M * (N >> 2);
    if (idx >= total) return;
    int nv = N >> 2;
    int r = idx / nv, c4 = (idx - r * nv) << 2;
    size_t off = (size_t)r * N + c4;
    size_t stride = (size_t)Mp * N;
    float4 v = *(const float4*)(P + off);
    for (int s = 1; s < S; s++) {
        float4 u = *(const float4*)(P + s * stride + off);
        v.x += u.x; v.y += u.y; v.z += u.z; v.w += u.w;
    }
    const float4 bv = *(const float4*)(bias + c4);
    v.x += bv.x; v.y += bv.y; v.z += bv.z; v.w += bv.w;
    v.x = v.x > 0.f ? v.x : 0.2f * v.x;
    v.y = v.y > 0.f ? v.y : 0.2f * v.y;
    v.z = v.z > 0.f ? v.z : 0.2f * v.z;
    v.w = v.w > 0.f ? v.w : 0.2f * v.w;
    bf16x4 o = { (bf16_t)v.x, (bf16_t)v.y, (bf16_t)v.z, (bf16_t)v.w };
    *(bf16x4*)(C + off) = o;
}

// -------- kernel 6: out[r] = H2[r,:512] . w2 + b2  (one wave per row) --------
__global__ __launch_bounds__(256) void final_kernel(
    const bf16_t* __restrict__ H2, const float* __restrict__ w2,
    const float* __restrict__ b2, float* __restrict__ out)
{
    int wid = (blockIdx.x * 256 + threadIdx.x) >> 6;
    int lane = threadIdx.x & 63;
    if (wid >= MROWS) return;
    const bf16_t* row = H2 + (size_t)wid * D1_;
    float s = 0.f;
    for (int i = 0; i < 8; i++) {
        int c = i * 64 + lane;
        s += (float)row[c] * w2[c];
    }
    for (int off = 32; off; off >>= 1) s += __shfl_down(s, off, 64);
    if (lane == 0) out[wid] = s + b2[0];
}

// ---------------------------- launcher ----------------------------
extern "C" void kernel_launch(void* const* d_in, const int* in_sizes, int n_in,
                              void* d_out, int out_size, void* d_ws, size_t ws_size,
                              hipStream_t stream)
{
    const float* input_    = (const float*)d_in[0];
    const float* graphs_x  = (const float*)d_in[1];
    const int*   edge_idx  = (const int*)  d_in[2];
    const int*   graph_ids = (const int*)  d_in[3];
    const float* chain     = (const float*)d_in[4];
    const float* metadata  = (const float*)d_in[5];
    const float* gcn_w     = (const float*)d_in[6];
    const float* gcn_b     = (const float*)d_in[7];
    const float* meta_w    = (const float*)d_in[8];
    const float* meta_b    = (const float*)d_in[9];
    const float* gme_w     = (const float*)d_in[10];
    const float* gme_b     = (const float*)d_in[11];
    const float* seq_w0    = (const float*)d_in[12];
    const float* seq_b0    = (const float*)d_in[13];
    const float* seq_w1    = (const float*)d_in[14];
    const float* seq_b1    = (const float*)d_in[15];
    const float* seq_w2    = (const float*)d_in[16];
    const float* seq_b2    = (const float*)d_in[17];
    float* out = (float*)d_out;

    char* ws = (char*)d_ws;
    // workspace layout
    float*  gnoise = (float*)(ws + 0);              //  64*128*4    =    32768
    float*  degs   = (float*)(ws + 32768);          //  64*2000*4   =   512000
    float*  outs   = (float*)(ws + 544768);         //  64*2000*4   =   512000
    bf16_t* Abuf   = (bf16_t*)(ws + 1056768);       // 1000*6400*2  = 12800000
    bf16_t* W0t    = (bf16_t*)(ws + 13856768);      // 1024*6400*2  = 13107200
    bf16_t* W1t    = (bf16_t*)(ws + 26963968);      //  512*1024*2  =  1048576
    bf16_t* H1     = (bf16_t*)(ws + 28012544);      // 1000*1024*2  =  2048000
    bf16_t* H2     = (bf16_t*)(ws + 30060544);      // 1000*512*2   =  1024000
    float*  P      = (float*)(ws + 31084544);       // 16 MB partials (reused)
    // total ~45.7 MB

    // GCN pipeline (degs+outs are contiguous: zero both in one kernel)
    zero_kernel<<<(2 * G_GRAPHS * N_NODES / 4 + 255) / 256, 256, 0, stream>>>(
        (float4*)degs, 2 * G_GRAPHS * N_NODES / 4);
    deg_kernel<<<dim3(ESPLIT, G_GRAPHS), 512, 0, stream>>>(edge_idx, degs);
    msg_kernel<<<dim3(ESPLIT, G_GRAPHS), 512, 0, stream>>>(graphs_x, edge_idx, degs, outs);
    gnoise_kernel<<<G_GRAPHS, 512, 0, stream>>>(graphs_x, degs, outs, gcn_w, gcn_b,
                                                gme_w, gnoise);

    pack_input_kernel<<<(BATCH * TED_ / 4 + 255) / 256, 256, 0, stream>>>(input_, Abuf);
    meta_noise_kernel<<<(BATCH * 64 + 255) / 256, 256, 0, stream>>>(
        chain, metadata, graph_ids, meta_w, meta_b, gme_w, gme_b, gnoise, Abuf);
    transpose_bf16_kernel<<<dim3(D0_ / 32, PACDIM_ / 32), 256, 0, stream>>>(
        seq_w0, W0t, PACDIM_, D0_);
    transpose_bf16_kernel<<<dim3(D1_ / 32, D0_ / 32), 256, 0, stream>>>(
        seq_w1, W1t, D0_, D1_);

    // layer 0: M=1000 N=1024 K=6400, split-K=4 (KS=1600) -> 8x8x4 = 256 blocks
    gemm_bt_splitk_kernel<<<dim3(D0_ / 128, 8, 4), 256, 0, stream>>>(
        Abuf, W0t, P, MROWS, D0_, PACDIM_, 1600);
    reduce_bias_leaky_kernel<<<(MROWS * D0_ / 4 + 255) / 256, 256, 0, stream>>>(
        P, seq_b0, H1, MROWS, D0_, 1024, 4);

    // layer 1: M=1000 N=512 K=1024, split-K=8 (KS=128) -> 4x8x8 = 256 blocks
    gemm_bt_splitk_kernel<<<dim3(D1_ / 128, 8, 8), 256, 0, stream>>>(
        H1, W1t, P, MROWS, D1_, D0_, 128);
    reduce_bias_leaky_kernel<<<(MROWS * D1_ / 4 + 255) / 256, 256, 0, stream>>>(
        P, seq_b1, H2, MROWS, D1_, 1024, 8);

    final_kernel<<<(MROWS * 64 + 255) / 256, 256, 0, stream>>>(H2, seq_w2, seq_b2, out);
}

// Round 3
// 276.440 us; speedup vs baseline: 1.8590x; 1.0932x over previous
//
#include <hip/hip_runtime.h>

typedef __bf16 bf16_t;
typedef __bf16 bf16x4 __attribute__((ext_vector_type(4)));
typedef __bf16 bf16x8 __attribute__((ext_vector_type(8)));
typedef float floatx4 __attribute__((ext_vector_type(4)));

#define G_GRAPHS 64
#define N_NODES 2000
#define N_EDGES 64000
#define BATCH 10000
#define TED_ 512
#define NOISE_ 128
#define PACDIM_ 6400
#define D0_ 1024
#define D1_ 512
#define MROWS 1000   // BATCH / PAC
#define ESPLIT 8
#define EPB (N_EDGES / ESPLIT)   // 8000 edges per block
#define S0 8          // split-K for layer 0
#define S1 8          // split-K for layer 1

// ---------------- async global->LDS helper (16B per lane) ----------------
__device__ __forceinline__ void glds16(const void* g, void* l) {
    __builtin_amdgcn_global_load_lds(
        (__attribute__((address_space(1))) void*)(g),
        (__attribute__((address_space(3))) void*)(l), 16, 0, 0);
}

// ------------- kernel 0: zero gnoise+degs+outs (contiguous region) -------------
__global__ __launch_bounds__(256) void zero_kernel(float4* __restrict__ p, int n4) {
    int i = blockIdx.x * 256 + threadIdx.x;
    if (i < n4) p[i] = make_float4(0.f, 0.f, 0.f, 0.f);
}

// ---------- kernel 1a: degree histogram, split over edges ----------
__global__ __launch_bounds__(512) void deg_kernel(
    const int* __restrict__ edge_index, float* __restrict__ degs)
{
    __shared__ float h[N_NODES];
    const int g = blockIdx.y, s = blockIdx.x, tid = threadIdx.x;
    for (int n = tid; n < N_NODES; n += 512) h[n] = 0.f;
    __syncthreads();
    const int* dst = edge_index + (size_t)g * 2 * N_EDGES + N_EDGES + s * EPB;
    for (int e = tid; e < EPB; e += 512) atomicAdd(&h[dst[e]], 1.0f);
    __syncthreads();
    float* dg = degs + (size_t)g * N_NODES;
    for (int n = tid; n < N_NODES; n += 512) {
        float v = h[n];
        if (v != 0.f) atomicAdd(&dg[n], v);
    }
}

// ---------- kernel 1b: message pass, split over edges ----------
__global__ __launch_bounds__(512) void msg_kernel(
    const float* __restrict__ graphs_x, const int* __restrict__ edge_index,
    const float* __restrict__ degs, float* __restrict__ outs)
{
    __shared__ float xsl[N_NODES];
    __shared__ float dvl[N_NODES];
    __shared__ float oh[N_NODES];
    const int g = blockIdx.y, s = blockIdx.x, tid = threadIdx.x;
    const float* xg = graphs_x + (size_t)g * N_NODES;
    const float* dgg = degs + (size_t)g * N_NODES;
    for (int n = tid; n < N_NODES; n += 512) {
        xsl[n] = xg[n];
        dvl[n] = rsqrtf(dgg[n] + 1.0f);   // +1 self-loop
        oh[n] = 0.f;
    }
    __syncthreads();
    const int* src = edge_index + (size_t)g * 2 * N_EDGES + s * EPB;
    const int* dst = src + N_EDGES;
    for (int e = tid; e < EPB; e += 512) {
        int ss = src[e], dd = dst[e];
        atomicAdd(&oh[dd], xsl[ss] * dvl[ss] * dvl[dd]);
    }
    __syncthreads();
    float* og = outs + (size_t)g * N_NODES;
    for (int n = tid; n < N_NODES; n += 512) {
        float v = oh[n];
        if (v != 0.f) atomicAdd(&og[n], v);
    }
}

// ---------- kernel 1c: finish gcn + gnoise[G,128] GEMV, split 4x over nodes ----------
__global__ __launch_bounds__(512) void gnoise_part_kernel(
    const float* __restrict__ graphs_x, const float* __restrict__ degs,
    const float* __restrict__ outs,
    const float* __restrict__ gcn_w, const float* __restrict__ gcn_b,
    const float* __restrict__ gme_w, float* __restrict__ gnoise)
{
    __shared__ float of[500];
    __shared__ float part[4][128];
    const int s = blockIdx.x, g = blockIdx.y, tid = threadIdx.x;
    const int nBase = s * 500;
    const float w = gcn_w[0], b = gcn_b[0];
    for (int n = tid; n < 500; n += 512) {
        int gn = nBase + n;
        float di2 = 1.0f / (degs[(size_t)g * N_NODES + gn] + 1.0f);
        of[n] = w * (outs[(size_t)g * N_NODES + gn]
                     + graphs_x[(size_t)g * N_NODES + gn] * di2) + b;
    }
    __syncthreads();
    const int j = tid & 127, ch = tid >> 7;
    float acc = 0.f;
    const int n0 = ch * 125;
    for (int n = n0; n < n0 + 125; n++)
        acc += of[n] * gme_w[(size_t)(nBase + n) * 128 + j];
    part[ch][j] = acc;
    __syncthreads();
    if (tid < 128)
        atomicAdd(&gnoise[(size_t)g * 128 + tid],
                  part[0][tid] + part[1][tid] + part[2][tid] + part[3][tid]);
}

// ------- kernel 2: pack input_ -> A bf16  AND  meta_emb+noise -> A noise cols -------
// blocks [0,5000): pack path; blocks [5000,7500): meta path
__global__ __launch_bounds__(256) void pack_meta_kernel(
    const float* __restrict__ in,
    const float* __restrict__ chain, const float* __restrict__ metadata,
    const int* __restrict__ graph_ids,
    const float* __restrict__ meta_w, const float* __restrict__ meta_b,
    const float* __restrict__ gme_w, const float* __restrict__ gme_b,
    const float* __restrict__ gnoise, bf16_t* __restrict__ A)
{
    if (blockIdx.x < 5000) {
        int idx = blockIdx.x * 256 + threadIdx.x;       // over BATCH*512/4
        float4 v = ((const float4*)in)[idx];
        int b = idx >> 7;
        int c = (idx & 127) << 2;
        int r = b / 10, slot = b - r * 10;
        bf16x4 o = { (bf16_t)v.x, (bf16_t)v.y, (bf16_t)v.z, (bf16_t)v.w };
        *(bf16x4*)(A + (size_t)r * PACDIM_ + slot * 640 + c) = o;
        return;
    }
    int wid = ((blockIdx.x - 5000) * 256 + threadIdx.x) >> 6;
    int lane = threadIdx.x & 63;
    if (wid >= BATCH) return;
    const int b = wid;
    float me = 0.f;
    if (lane < 32) {
        me = meta_b[lane] + chain[b] * meta_w[lane];
        for (int i = 1; i < 16; i++)
            me += metadata[(size_t)b * 15 + (i - 1)] * meta_w[(size_t)i * 32 + lane];
        me = me > 0.f ? me : 0.f;
    }
    const int gid = graph_ids[b];
    const int j1 = lane, j2 = lane + 64;
    float n1 = gnoise[(size_t)gid * 128 + j1] + gme_b[j1];
    float n2 = gnoise[(size_t)gid * 128 + j2] + gme_b[j2];
    for (int k = 0; k < 32; k++) {
        float mk = __shfl(me, k, 64);
        const float* wrow = gme_w + (size_t)(N_NODES + k) * 128;
        n1 += mk * wrow[j1];
        n2 += mk * wrow[j2];
    }
    int r = b / 10, slot = b - r * 10;
    bf16_t* dp = A + (size_t)r * PACDIM_ + slot * 640 + TED_;
    dp[j1] = (bf16_t)n1;
    dp[j2] = (bf16_t)n2;
}

// -------- kernel 4: transpose-convert W [R,C] fp32 -> Wt [C,R] bf16 --------
__global__ __launch_bounds__(256) void transpose_bf16_kernel(
    const float* __restrict__ W, bf16_t* __restrict__ Wt, int R, int C)
{
    __shared__ float t[32][33];
    int c0 = blockIdx.x * 32, r0 = blockIdx.y * 32;
    int tx = threadIdx.x & 31, ty = threadIdx.x >> 5;
    for (int yy = ty; yy < 32; yy += 8)
        t[yy][tx] = W[(size_t)(r0 + yy) * C + c0 + tx];
    __syncthreads();
    for (int yy = ty; yy < 32; yy += 8)
        Wt[(size_t)(c0 + yy) * R + r0 + tx] = (bf16_t)t[tx][yy];
}

// -------- kernel 5: split-K GEMM partial: P[z] = A[M,Kslice] @ Bt^T --------
// BM=BN=128, BK=32, 256 thr = 4 waves; blockIdx.z = K-split index
__global__ __launch_bounds__(256) void gemm_bt_splitk_kernel(
    const bf16_t* __restrict__ A,   // [M,K] row-major
    const bf16_t* __restrict__ Bt,  // [N,K] row-major
    float* __restrict__ P,          // [S, Mp, N] fp32 partials
    int M, int N, int K, int KS)    // KS = K slice per split
{
    __shared__ __align__(16) bf16_t As[128 * 32];
    __shared__ __align__(16) bf16_t Bs[128 * 32];
    const int tid = threadIdx.x;
    const int wave = tid >> 6;
    const int lane = tid & 63;
    const int mBase = blockIdx.y * 128;
    const int nBase = blockIdx.x * 128;
    const int z = blockIdx.z;
    const int Mp = gridDim.y * 128;
    const int wm = (wave & 1) * 64;
    const int wn = (wave >> 1) * 64;

    floatx4 acc[4][4] = {};

    const int c0 = tid, c1 = tid + 256;
    const int rA0 = c0 >> 2, k80 = (c0 & 3) * 8;
    const int rA1 = c1 >> 2, k81 = (c1 & 3) * 8;
    int gm0 = mBase + rA0; if (gm0 > M - 1) gm0 = M - 1;
    int gm1 = mBase + rA1; if (gm1 > M - 1) gm1 = M - 1;
    const bf16_t* aP0 = A + (size_t)gm0 * K + k80;
    const bf16_t* aP1 = A + (size_t)gm1 * K + k81;
    const bf16_t* bP0 = Bt + (size_t)(nBase + rA0) * K + k80;
    const bf16_t* bP1 = Bt + (size_t)(nBase + rA1) * K + k81;
    char* lA0 = (char*)As + wave * 1024;
    char* lA1 = (char*)As + 4096 + wave * 1024;
    char* lB0 = (char*)Bs + wave * 1024;
    char* lB1 = (char*)Bs + 4096 + wave * 1024;

    const int kq = (lane >> 4) * 8;
    const int mr = lane & 15;
    const bf16x8* ra[4]; const bf16x8* rb[4];
    for (int i = 0; i < 4; i++)
        ra[i] = (const bf16x8*)&As[(wm + i * 16 + mr) * 32 + kq];
    for (int j = 0; j < 4; j++)
        rb[j] = (const bf16x8*)&Bs[(wn + j * 16 + mr) * 32 + kq];

    const int kEnd = z * KS + KS;
    for (int k0 = z * KS; k0 < kEnd; k0 += 32) {
        __syncthreads();
        glds16(aP0 + k0, lA0);
        glds16(aP1 + k0, lA1);
        glds16(bP0 + k0, lB0);
        glds16(bP1 + k0, lB1);
        __syncthreads();
        bf16x8 af[4], bfr[4];
        for (int i = 0; i < 4; i++) af[i] = *ra[i];
        for (int j = 0; j < 4; j++) bfr[j] = *rb[j];
        for (int i = 0; i < 4; i++)
            for (int j = 0; j < 4; j++)
                acc[i][j] = __builtin_amdgcn_mfma_f32_16x16x32_bf16(
                    af[i], bfr[j], acc[i][j], 0, 0, 0);
    }

    float* Pz = P + (size_t)z * Mp * N;
    const int rq = (lane >> 4) * 4;
    const int cn = lane & 15;
    for (int j = 0; j < 4; j++) {
        int col = nBase + wn + j * 16 + cn;
        for (int i = 0; i < 4; i++)
            for (int r = 0; r < 4; r++) {
                int rowm = mBase + wm + i * 16 + rq + r;
                Pz[(size_t)rowm * N + col] = acc[i][j][r];
            }
    }
}

// -------- kernel 5b: reduce split-K partials + bias + leaky -> bf16 --------
__global__ __launch_bounds__(256) void reduce_bias_leaky_kernel(
    const float* __restrict__ P, const float* __restrict__ bias,
    bf16_t* __restrict__ C, int M, int N, int Mp, int S)
{
    int idx = blockIdx.x * 256 + threadIdx.x;
    int total = M * (N >> 2);
    if (idx >= total) return;
    int nv = N >> 2;
    int r = idx / nv, c4 = (idx - r * nv) << 2;
    size_t off = (size_t)r * N + c4;
    size_t stride = (size_t)Mp * N;
    float4 v = *(const float4*)(P + off);
    for (int s = 1; s < S; s++) {
        float4 u = *(const float4*)(P + s * stride + off);
        v.x += u.x; v.y += u.y; v.z += u.z; v.w += u.w;
    }
    const float4 bv = *(const float4*)(bias + c4);
    v.x += bv.x; v.y += bv.y; v.z += bv.z; v.w += bv.w;
    v.x = v.x > 0.f ? v.x : 0.2f * v.x;
    v.y = v.y > 0.f ? v.y : 0.2f * v.y;
    v.z = v.z > 0.f ? v.z : 0.2f * v.z;
    v.w = v.w > 0.f ? v.w : 0.2f * v.w;
    bf16x4 o = { (bf16_t)v.x, (bf16_t)v.y, (bf16_t)v.z, (bf16_t)v.w };
    *(bf16x4*)(C + off) = o;
}

// ---- kernel 6: fused reduce(P1) + bias + leaky + dot(w2) + b2 -> out[r] ----
// one wave per output row; lane covers 8 cols strided by 64
__global__ __launch_bounds__(256) void final_fused_kernel(
    const float* __restrict__ P, const float* __restrict__ b1,
    const float* __restrict__ w2, const float* __restrict__ b2,
    float* __restrict__ out, int Mp, int S)
{
    int wid = (blockIdx.x * 256 + threadIdx.x) >> 6;
    int lane = threadIdx.x & 63;
    if (wid >= MROWS) return;
    size_t stride = (size_t)Mp * D1_;
    const float* base = P + (size_t)wid * D1_;
    float s = 0.f;
    for (int i = 0; i < 8; i++) {
        int c = i * 64 + lane;
        float v = base[c];
        for (int z = 1; z < S; z++) v += base[(size_t)z * stride + c];
        v += b1[c];
        v = v > 0.f ? v : 0.2f * v;
        s += v * w2[c];
    }
    for (int off = 32; off; off >>= 1) s += __shfl_down(s, off, 64);
    if (lane == 0) out[wid] = s + b2[0];
}

// ---------------------------- launcher ----------------------------
extern "C" void kernel_launch(void* const* d_in, const int* in_sizes, int n_in,
                              void* d_out, int out_size, void* d_ws, size_t ws_size,
                              hipStream_t stream)
{
    const float* input_    = (const float*)d_in[0];
    const float* graphs_x  = (const float*)d_in[1];
    const int*   edge_idx  = (const int*)  d_in[2];
    const int*   graph_ids = (const int*)  d_in[3];
    const float* chain     = (const float*)d_in[4];
    const float* metadata  = (const float*)d_in[5];
    const float* gcn_w     = (const float*)d_in[6];
    const float* gcn_b     = (const float*)d_in[7];
    const float* meta_w    = (const float*)d_in[8];
    const float* meta_b    = (const float*)d_in[9];
    const float* gme_w     = (const float*)d_in[10];
    const float* gme_b     = (const float*)d_in[11];
    const float* seq_w0    = (const float*)d_in[12];
    const float* seq_b0    = (const float*)d_in[13];
    const float* seq_w1    = (const float*)d_in[14];
    const float* seq_b1    = (const float*)d_in[15];
    const float* seq_w2    = (const float*)d_in[16];
    const float* seq_b2    = (const float*)d_in[17];
    float* out = (float*)d_out;

    char* ws = (char*)d_ws;
    // workspace layout (gnoise|degs|outs contiguous for one-shot zeroing)
    float*  gnoise = (float*)(ws + 0);              //  64*128*4    =    32768
    float*  degs   = (float*)(ws + 32768);          //  64*2000*4   =   512000
    float*  outs   = (float*)(ws + 544768);         //  64*2000*4   =   512000
    bf16_t* Abuf   = (bf16_t*)(ws + 1056768);       // 1000*6400*2  = 12800000
    bf16_t* W0t    = (bf16_t*)(ws + 13856768);      // 1024*6400*2  = 13107200
    bf16_t* W1t    = (bf16_t*)(ws + 26963968);      //  512*1024*2  =  1048576
    bf16_t* H1     = (bf16_t*)(ws + 28012544);      // 1000*1024*2  =  2048000
    float*  P      = (float*)(ws + 30060544);       // 8*1024*1024*4 = 33554432
    // total ~60.7 MB

    const int zn4 = (32768 + 512000 + 512000) / 16;   // 66048 float4
    zero_kernel<<<(zn4 + 255) / 256, 256, 0, stream>>>((float4*)gnoise, zn4);
    deg_kernel<<<dim3(ESPLIT, G_GRAPHS), 512, 0, stream>>>(edge_idx, degs);
    msg_kernel<<<dim3(ESPLIT, G_GRAPHS), 512, 0, stream>>>(graphs_x, edge_idx, degs, outs);
    gnoise_part_kernel<<<dim3(4, G_GRAPHS), 512, 0, stream>>>(
        graphs_x, degs, outs, gcn_w, gcn_b, gme_w, gnoise);

    pack_meta_kernel<<<7500, 256, 0, stream>>>(
        input_, chain, metadata, graph_ids, meta_w, meta_b, gme_w, gme_b,
        gnoise, Abuf);
    transpose_bf16_kernel<<<dim3(D0_ / 32, PACDIM_ / 32), 256, 0, stream>>>(
        seq_w0, W0t, PACDIM_, D0_);
    transpose_bf16_kernel<<<dim3(D1_ / 32, D0_ / 32), 256, 0, stream>>>(
        seq_w1, W1t, D0_, D1_);

    // layer 0: M=1000 N=1024 K=6400, split-K=8 (KS=800) -> 8x8x8 = 512 blocks
    gemm_bt_splitk_kernel<<<dim3(D0_ / 128, 8, S0), 256, 0, stream>>>(
        Abuf, W0t, P, MROWS, D0_, PACDIM_, PACDIM_ / S0);
    reduce_bias_leaky_kernel<<<(MROWS * D0_ / 4 + 255) / 256, 256, 0, stream>>>(
        P, seq_b0, H1, MROWS, D0_, 1024, S0);

    // layer 1: M=1000 N=512 K=1024, split-K=8 (KS=128) -> 4x8x8 = 256 blocks
    gemm_bt_splitk_kernel<<<dim3(D1_ / 128, 8, S1), 256, 0, stream>>>(
        H1, W1t, P, MROWS, D1_, D0_, D0_ / S1);
    // fused: reduce P1 + bias + leaky + dot w2 + b2 -> out
    final_fused_kernel<<<(MROWS * 64 + 255) / 256, 256, 0, stream>>>(
        P, seq_b1, seq_w2, seq_b2, out, 1024, S1);
}